// Round 2
// baseline (718.904 us; speedup 1.0000x reference)
//
#include <hip/hip_runtime.h>

// Problem constants
#define B_  4
#define H_  12
#define L_  1024
#define DK_ 64
#define GH_ 8      // global attention heads
#define LH_ 4      // local value heads
#define NG_ 4      // gru parameter sets
#define WS_ 9      // gru window steps (INIT_VAL+1)

#define ATTN_LDS_BYTES (4 * 64 * 68 * 4)                                  // 69,632
#define GRU_LDS_WORDS  (64*196 + 72*196 + 64*68 + 64*132 + 384)
#define GRU_LDS_BYTES  (GRU_LDS_WORDS * 4)                                // 159,360

// acc[i][j] += sum_e a4[i].e * b4[e].j  (4x4x4 register-tile FMA)
__device__ __forceinline__ void gemm4x4(float acc[4][4], const float4* a4, const float4* b4) {
#pragma unroll
  for (int i = 0; i < 4; ++i) {
    const float av[4] = {a4[i].x, a4[i].y, a4[i].z, a4[i].w};
#pragma unroll
    for (int e = 0; e < 4; ++e) {
      acc[i][0] = fmaf(av[e], b4[e].x, acc[i][0]);
      acc[i][1] = fmaf(av[e], b4[e].y, acc[i][1]);
      acc[i][2] = fmaf(av[e], b4[e].z, acc[i][2]);
      acc[i][3] = fmaf(av[e], b4[e].w, acc[i][3]);
    }
  }
}

// ---------------- Global attention (heads 0..7), f32 flash ----------------
// grid (L/64, 8, B), block 256. Per block: 64 q-rows, loop 16 k-tiles of 64.
// Thread (tr,tc) owns rows 4tr..+3, cols/dims 4tc..+3. Softmax state (m,l)
// and O accumulator live entirely in registers (16-lane shfl reductions).
__global__ __launch_bounds__(256) void attn_kernel(
    const float* __restrict__ q, const float* __restrict__ k,
    const float* __restrict__ v, const int* __restrict__ mask,
    float* __restrict__ out)
{
  extern __shared__ float sm[];
  float* sQ  = sm;                 // [64][68] row-major
  float* sKT = sQ  + 64 * 68;      // [64][68]: sKT[d][c] = K[c][d] (transposed)
  float* sV  = sKT + 64 * 68;      // [64][68] row-major
  float* sP  = sV  + 64 * 68;      // [64][68] row-major

  const int tid = threadIdx.x;
  const int q0 = blockIdx.x * 64;
  const int h  = blockIdx.y;
  const int b  = blockIdx.z;

  const float* qp = q + (((size_t)b * H_ + h) * L_ + q0) * DK_;
  const float* kp = k + (((size_t)b * H_ + h) * L_) * DK_;
  const float* vp = v + (((size_t)b * H_ + h) * L_) * DK_;
  const int*   mp = mask + (size_t)b * L_ * L_ + (size_t)q0 * L_;
  float*       op = out + (((size_t)b * 24 + h) * L_ + q0) * DK_;

  for (int t = tid; t < 64 * 16; t += 256) {
    const int r = t >> 4, c4 = (t & 15) << 2;
    *(float4*)(sQ + r * 68 + c4) = *(const float4*)(qp + r * DK_ + c4);
  }

  const int tr = tid >> 4, tc = tid & 15;
  const int r0 = tr << 2, c0 = tc << 2;

  float o_[4][4];
  float mrun[4], lrun[4];
#pragma unroll
  for (int i = 0; i < 4; ++i) {
    mrun[i] = -1e30f; lrun[i] = 0.f;
#pragma unroll
    for (int j = 0; j < 4; ++j) o_[i][j] = 0.f;
  }

  __syncthreads();

  for (int kt = 0; kt < 16; ++kt) {
    const float* kpt = kp + (size_t)kt * 64 * DK_;
    const float* vpt = vp + (size_t)kt * 64 * DK_;
    for (int t = tid; t < 64 * 16; t += 256) {
      const int r = t >> 4, c4 = (t & 15) << 2;
      const float4 kv = *(const float4*)(kpt + r * DK_ + c4);
      sKT[(c4 + 0) * 68 + r] = kv.x;
      sKT[(c4 + 1) * 68 + r] = kv.y;
      sKT[(c4 + 2) * 68 + r] = kv.z;
      sKT[(c4 + 3) * 68 + r] = kv.w;
      *(float4*)(sV + r * 68 + c4) = *(const float4*)(vpt + r * DK_ + c4);
    }
    __syncthreads();

    // S = Q K^T (4x4 per thread)
    float acc[4][4] = {};
#pragma unroll 4
    for (int dd = 0; dd < 64; dd += 4) {
      float4 a4[4], b4[4];
#pragma unroll
      for (int i = 0; i < 4; ++i) a4[i] = *(const float4*)(sQ + (r0 + i) * 68 + dd);
#pragma unroll
      for (int e = 0; e < 4; ++e) b4[e] = *(const float4*)(sKT + (dd + e) * 68 + c0);
      gemm4x4(acc, a4, b4);
    }

    // mask + online softmax (per row; 16 tc-lanes of a row are in one wave)
#pragma unroll
    for (int i = 0; i < 4; ++i) {
      const int4 mv = *(const int4*)(mp + (size_t)(r0 + i) * L_ + kt * 64 + c0);
      const float s0_ = (mv.x == 0) ? -1e12f : acc[i][0] * 0.125f;
      const float s1_ = (mv.y == 0) ? -1e12f : acc[i][1] * 0.125f;
      const float s2_ = (mv.z == 0) ? -1e12f : acc[i][2] * 0.125f;
      const float s3_ = (mv.w == 0) ? -1e12f : acc[i][3] * 0.125f;
      float mt = fmaxf(fmaxf(s0_, s1_), fmaxf(s2_, s3_));
#pragma unroll
      for (int off = 1; off < 16; off <<= 1) mt = fmaxf(mt, __shfl_xor(mt, off));
      const float mnew = fmaxf(mrun[i], mt);
      const float p0 = expf(s0_ - mnew);
      const float p1 = expf(s1_ - mnew);
      const float p2 = expf(s2_ - mnew);
      const float p3 = expf(s3_ - mnew);
      float pt = p0 + p1 + p2 + p3;
#pragma unroll
      for (int off = 1; off < 16; off <<= 1) pt += __shfl_xor(pt, off);
      const float scale = expf(mrun[i] - mnew);
      mrun[i] = mnew;
      lrun[i] = lrun[i] * scale + pt;
      o_[i][0] *= scale; o_[i][1] *= scale; o_[i][2] *= scale; o_[i][3] *= scale;
      float4 pw; pw.x = p0; pw.y = p1; pw.z = p2; pw.w = p3;
      *(float4*)(sP + (r0 + i) * 68 + c0) = pw;
    }
    __syncthreads();

    // O += P V (thread's dims are d0 = c0)
#pragma unroll 4
    for (int cc = 0; cc < 64; cc += 4) {
      float4 a4[4], b4[4];
#pragma unroll
      for (int i = 0; i < 4; ++i) a4[i] = *(const float4*)(sP + (r0 + i) * 68 + cc);
#pragma unroll
      for (int e = 0; e < 4; ++e) b4[e] = *(const float4*)(sV + (cc + e) * 68 + c0);
      gemm4x4(o_, a4, b4);
    }
    __syncthreads();
  }

#pragma unroll
  for (int i = 0; i < 4; ++i) {
    const float inv = 1.f / lrun[i];
    float4 r_;
    r_.x = o_[i][0] * inv; r_.y = o_[i][1] * inv;
    r_.z = o_[i][2] * inv; r_.w = o_[i][3] * inv;
    *(float4*)(op + (size_t)(r0 + i) * DK_ + c0) = r_;
  }
}

// ---------------- GRU over sliding windows (heads 8..23), f32 ----------------
// grid (L/64, NG*LH, B), block 256. Block = (b, vh, g, 64-sequence l-tile).
// Key: xg[l, t] = W_ih v[l+t] + b_ih depends only on pos = l+t, so compute it
// once per position (72 positions incl. halo) instead of per (seq, t).
// Then 9 synchronized GRU steps; gh GEMM split into [r|z] then [n] so that r
// is in registers before hn is consumed, letting gh_n reuse the gh_rz buffer.
__global__ __launch_bounds__(256) void gru_kernel(
    const float* __restrict__ value, const float* __restrict__ wih_g,
    const float* __restrict__ whh_g, const float* __restrict__ bih_g,
    const float* __restrict__ bhh_g, float* __restrict__ out)
{
  extern __shared__ float sm[];
  float* sWT  = sm;                    // [64][196]: sWT[d][j] = W[j][d] (transposed)
  float* sXG  = sWT + 64 * 196;        // [72][196]: input transform per position
  float* sH   = sXG + 72 * 196;        // [64][68]:  hidden states
  float* sGRZ = sH  + 64 * 68;         // [64][132]: gh buffer (rz, then n)
  float* sBih = sGRZ + 64 * 132;       // [192]
  float* sBhh = sBih + 192;            // [192]
  float* sVl  = sGRZ;                  // phase-1 alias: v tile [72][68]

  const int tid = threadIdx.x;
  const int l0 = blockIdx.x * 64;
  const int g  = blockIdx.y >> 2;
  const int vh = blockIdx.y & 3;
  const int b  = blockIdx.z;

  const float* vp  = value + (((size_t)b * H_ + GH_ + vh) * L_) * DK_;
  const float* wih = wih_g + (size_t)g * 192 * DK_;
  const float* whh = whh_g + (size_t)g * 192 * DK_;

  if (tid < 192) {
    sBih[tid] = bih_g[g * 192 + tid];
    sBhh[tid] = bhh_g[g * 192 + tid];
  }

  // stage W_ih transposed
  for (int t = tid; t < 192 * 16; t += 256) {
    const int j = t >> 4, d4 = (t & 15) << 2;
    const float4 wv = *(const float4*)(wih + j * DK_ + d4);
    sWT[(d4 + 0) * 196 + j] = wv.x;
    sWT[(d4 + 1) * 196 + j] = wv.y;
    sWT[(d4 + 2) * 196 + j] = wv.z;
    sWT[(d4 + 3) * 196 + j] = wv.w;
  }
  // stage v positions l0..l0+71 (zero-padded past L)
  for (int t = tid; t < 72 * 16; t += 256) {
    const int p = t >> 4, c4 = (t & 15) << 2;
    const int gp = l0 + p;
    float4 vv;
    if (gp < L_) vv = *(const float4*)(vp + (size_t)gp * DK_ + c4);
    else { vv.x = 0.f; vv.y = 0.f; vv.z = 0.f; vv.w = 0.f; }
    *(float4*)(sVl + p * 68 + c4) = vv;
  }
  __syncthreads();

  // phase 1: sXG[p][j] = sum_d v[p][d] * W_ih[j][d] + b_ih[j]
  for (int t = tid; t < 18 * 48; t += 256) {
    const int p0 = (t / 48) << 2;
    const int j0 = (t % 48) << 2;
    float acc[4][4] = {};
#pragma unroll 4
    for (int dd = 0; dd < 64; dd += 4) {
      float4 a4[4], b4[4];
#pragma unroll
      for (int i = 0; i < 4; ++i) a4[i] = *(const float4*)(sVl + (p0 + i) * 68 + dd);
#pragma unroll
      for (int e = 0; e < 4; ++e) b4[e] = *(const float4*)(sWT + (dd + e) * 196 + j0);
      gemm4x4(acc, a4, b4);
    }
#pragma unroll
    for (int i = 0; i < 4; ++i) {
      float4 stv;
      stv.x = acc[i][0] + sBih[j0 + 0];
      stv.y = acc[i][1] + sBih[j0 + 1];
      stv.z = acc[i][2] + sBih[j0 + 2];
      stv.w = acc[i][3] + sBih[j0 + 3];
      *(float4*)(sXG + (p0 + i) * 196 + j0) = stv;
    }
  }
  __syncthreads();

  // restage W = W_hh transposed; zero hidden states
  for (int t = tid; t < 192 * 16; t += 256) {
    const int j = t >> 4, d4 = (t & 15) << 2;
    const float4 wv = *(const float4*)(whh + j * DK_ + d4);
    sWT[(d4 + 0) * 196 + j] = wv.x;
    sWT[(d4 + 1) * 196 + j] = wv.y;
    sWT[(d4 + 2) * 196 + j] = wv.z;
    sWT[(d4 + 3) * 196 + j] = wv.w;
  }
  for (int t = tid; t < 64 * 68; t += 256) sH[t] = 0.f;
  __syncthreads();

  const int s  = tid >> 2;          // sequence owned in gate phases
  const int db = (tid & 3) << 4;    // dim base (16 dims per thread)
  float rg[16], zg[16];

  for (int ts = 0; ts < WS_; ++ts) {
    // GEMM rz: gh[s][j] = h[s]·W_hh[j] + b_hh[j], j in [0,128)
    for (int t = tid; t < 512; t += 256) {
      const int s4 = (t >> 5) << 2;
      const int j0 = (t & 31) << 2;
      float acc[4][4] = {};
#pragma unroll 4
      for (int dd = 0; dd < 64; dd += 4) {
        float4 a4[4], b4[4];
#pragma unroll
        for (int i = 0; i < 4; ++i) a4[i] = *(const float4*)(sH + (s4 + i) * 68 + dd);
#pragma unroll
        for (int e = 0; e < 4; ++e) b4[e] = *(const float4*)(sWT + (dd + e) * 196 + j0);
        gemm4x4(acc, a4, b4);
      }
#pragma unroll
      for (int i = 0; i < 4; ++i) {
        float4 stv;
        stv.x = acc[i][0] + sBhh[j0 + 0];
        stv.y = acc[i][1] + sBhh[j0 + 1];
        stv.z = acc[i][2] + sBhh[j0 + 2];
        stv.w = acc[i][3] + sBhh[j0 + 3];
        *(float4*)(sGRZ + (s4 + i) * 132 + j0) = stv;
      }
    }
    __syncthreads();

    // gates r, z (kept in registers across the n-GEMM)
    const int pos = s + ts;
#pragma unroll
    for (int i = 0; i < 16; ++i) {
      const int d = db + i;
      const float xr = sXG[pos * 196 + d];
      const float xz = sXG[pos * 196 + 64 + d];
      const float hr = sGRZ[s * 132 + d];
      const float hz = sGRZ[s * 132 + 64 + d];
      rg[i] = 1.f / (1.f + expf(-(xr + hr)));
      zg[i] = 1.f / (1.f + expf(-(xz + hz)));
    }
    __syncthreads();

    // GEMM n: gh_n[s][d] = h[s]·W_hh[128+d] + b_hh[128+d] -> sGRZ[s][0..64)
    {
      const int s4 = (tid >> 4) << 2;
      const int j0 = (tid & 15) << 2;
      float acc[4][4] = {};
#pragma unroll 4
      for (int dd = 0; dd < 64; dd += 4) {
        float4 a4[4], b4[4];
#pragma unroll
        for (int i = 0; i < 4; ++i) a4[i] = *(const float4*)(sH + (s4 + i) * 68 + dd);
#pragma unroll
        for (int e = 0; e < 4; ++e) b4[e] = *(const float4*)(sWT + (dd + e) * 196 + 128 + j0);
        gemm4x4(acc, a4, b4);
      }
#pragma unroll
      for (int i = 0; i < 4; ++i) {
        float4 stv;
        stv.x = acc[i][0] + sBhh[128 + j0 + 0];
        stv.y = acc[i][1] + sBhh[128 + j0 + 1];
        stv.z = acc[i][2] + sBhh[128 + j0 + 2];
        stv.w = acc[i][3] + sBhh[128 + j0 + 3];
        *(float4*)(sGRZ + (s4 + i) * 132 + j0) = stv;
      }
    }
    __syncthreads();

    // gates n + hidden update
#pragma unroll
    for (int i = 0; i < 16; ++i) {
      const int d = db + i;
      const float xn = sXG[pos * 196 + 128 + d];
      const float hn = sGRZ[s * 132 + d];
      const float nn = tanhf(xn + rg[i] * hn);
      const float hold = sH[s * 68 + d];
      sH[s * 68 + d] = (1.f - zg[i]) * nn + zg[i] * hold;
    }
    __syncthreads();
  }

  // write final hidden: out channel 8 + g*4 + vh, rows l0..l0+63
  float* op = out + (((size_t)b * 24 + (GH_ + (g << 2) + vh)) * L_ + l0) * DK_;
  for (int t = tid; t < 64 * 16; t += 256) {
    const int r = t >> 4, c4 = (t & 15) << 2;
    *(float4*)(op + r * DK_ + c4) = *(const float4*)(sH + r * 68 + c4);
  }
}

extern "C" void kernel_launch(void* const* d_in, const int* in_sizes, int n_in,
                              void* d_out, int out_size, void* d_ws, size_t ws_size,
                              hipStream_t stream) {
  (void)in_sizes; (void)n_in; (void)d_ws; (void)ws_size; (void)out_size;
  const float* q   = (const float*)d_in[0];
  const float* k   = (const float*)d_in[1];
  const float* v   = (const float*)d_in[2];
  const int*   msk = (const int*)d_in[3];
  const float* wih = (const float*)d_in[4];
  const float* whh = (const float*)d_in[5];
  const float* bih = (const float*)d_in[6];
  const float* bhh = (const float*)d_in[7];
  float* out = (float*)d_out;

  // opt in to >64KB dynamic LDS (gfx950 allows up to 160KB/workgroup)
  (void)hipFuncSetAttribute((const void*)attn_kernel,
                            hipFuncAttributeMaxDynamicSharedMemorySize, ATTN_LDS_BYTES);
  (void)hipFuncSetAttribute((const void*)gru_kernel,
                            hipFuncAttributeMaxDynamicSharedMemorySize, GRU_LDS_BYTES);

  attn_kernel<<<dim3(L_ / 64, GH_, B_), dim3(256), ATTN_LDS_BYTES, stream>>>(q, k, v, msk, out);
  gru_kernel<<<dim3(L_ / 64, NG_ * LH_, B_), dim3(256), GRU_LDS_BYTES, stream>>>(v, wih, whh, bih, bhh, out);
}

// Round 3
// 431.736 us; speedup vs baseline: 1.6651x; 1.6651x over previous
//
#include <hip/hip_runtime.h>

// Problem constants
#define B_  4
#define H_  12
#define L_  1024
#define DK_ 64
#define GH_ 8      // global attention heads
#define WS_ 9      // gru window steps (INIT_VAL+1)

#define ATTN_LDS_BYTES (4 * 64 * 68 * 4)   // 69,632
// GRU LDS: W_hh bf16 [192][64] swz (24576) + XG bf16 [144][196] (56448)
//        + h-buf 8 waves * (hi 2048 + lo 2048) (32768) + b_ih f32 [192] (768)
#define GRU_W_OFF   0
#define GRU_XG_OFF  24576
#define GRU_HB_OFF  81024
#define GRU_BIH_OFF 113792
#define GRU_LDS_BYTES 114560

typedef __attribute__((ext_vector_type(8))) short short8;
typedef __attribute__((ext_vector_type(4))) float f32x4;

#define MFMA_BF16(a, b, c) __builtin_amdgcn_mfma_f32_16x16x32_bf16((a), (b), (c), 0, 0, 0)

__device__ __forceinline__ unsigned short f2bf(float f) {  // f32 -> bf16 bits, RNE
  unsigned int u = __builtin_bit_cast(unsigned int, f);
  u += 0x7fffu + ((u >> 16) & 1u);
  return (unsigned short)(u >> 16);
}
__device__ __forceinline__ float bf2f(unsigned short s) {  // bf16 bits -> f32 (exact)
  return __builtin_bit_cast(float, ((unsigned int)s) << 16);
}
__device__ __forceinline__ short8 pack8(const float4 a, const float4 b) {
  short8 r;
  r[0] = (short)f2bf(a.x); r[1] = (short)f2bf(a.y);
  r[2] = (short)f2bf(a.z); r[3] = (short)f2bf(a.w);
  r[4] = (short)f2bf(b.x); r[5] = (short)f2bf(b.y);
  r[6] = (short)f2bf(b.z); r[7] = (short)f2bf(b.w);
  return r;
}

// acc[i][j] += sum_e a4[i].e * b4[e].j  (4x4x4 register-tile FMA) -- attn only
__device__ __forceinline__ void gemm4x4(float acc[4][4], const float4* a4, const float4* b4) {
#pragma unroll
  for (int i = 0; i < 4; ++i) {
    const float av[4] = {a4[i].x, a4[i].y, a4[i].z, a4[i].w};
#pragma unroll
    for (int e = 0; e < 4; ++e) {
      acc[i][0] = fmaf(av[e], b4[e].x, acc[i][0]);
      acc[i][1] = fmaf(av[e], b4[e].y, acc[i][1]);
      acc[i][2] = fmaf(av[e], b4[e].z, acc[i][2]);
      acc[i][3] = fmaf(av[e], b4[e].w, acc[i][3]);
    }
  }
}

// ---------------- Global attention (heads 0..7), f32 flash (unchanged) ------
__global__ __launch_bounds__(256) void attn_kernel(
    const float* __restrict__ q, const float* __restrict__ k,
    const float* __restrict__ v, const int* __restrict__ mask,
    float* __restrict__ out)
{
  extern __shared__ float sm[];
  float* sQ  = sm;                 // [64][68]
  float* sKT = sQ  + 64 * 68;      // [64][68] transposed K
  float* sV  = sKT + 64 * 68;      // [64][68]
  float* sP  = sV  + 64 * 68;      // [64][68]

  const int tid = threadIdx.x;
  const int q0 = blockIdx.x * 64;
  const int h  = blockIdx.y;
  const int b  = blockIdx.z;

  const float* qp = q + (((size_t)b * H_ + h) * L_ + q0) * DK_;
  const float* kp = k + (((size_t)b * H_ + h) * L_) * DK_;
  const float* vp = v + (((size_t)b * H_ + h) * L_) * DK_;
  const int*   mp = mask + (size_t)b * L_ * L_ + (size_t)q0 * L_;
  float*       op = out + (((size_t)b * 24 + h) * L_ + q0) * DK_;

  for (int t = tid; t < 64 * 16; t += 256) {
    const int r = t >> 4, c4 = (t & 15) << 2;
    *(float4*)(sQ + r * 68 + c4) = *(const float4*)(qp + r * DK_ + c4);
  }

  const int tr = tid >> 4, tc = tid & 15;
  const int r0 = tr << 2, c0 = tc << 2;

  float o_[4][4];
  float mrun[4], lrun[4];
#pragma unroll
  for (int i = 0; i < 4; ++i) {
    mrun[i] = -1e30f; lrun[i] = 0.f;
#pragma unroll
    for (int j = 0; j < 4; ++j) o_[i][j] = 0.f;
  }

  __syncthreads();

  for (int kt = 0; kt < 16; ++kt) {
    const float* kpt = kp + (size_t)kt * 64 * DK_;
    const float* vpt = vp + (size_t)kt * 64 * DK_;
    for (int t = tid; t < 64 * 16; t += 256) {
      const int r = t >> 4, c4 = (t & 15) << 2;
      const float4 kv = *(const float4*)(kpt + r * DK_ + c4);
      sKT[(c4 + 0) * 68 + r] = kv.x;
      sKT[(c4 + 1) * 68 + r] = kv.y;
      sKT[(c4 + 2) * 68 + r] = kv.z;
      sKT[(c4 + 3) * 68 + r] = kv.w;
      *(float4*)(sV + r * 68 + c4) = *(const float4*)(vpt + r * DK_ + c4);
    }
    __syncthreads();

    float acc[4][4] = {};
#pragma unroll 4
    for (int dd = 0; dd < 64; dd += 4) {
      float4 a4[4], b4[4];
#pragma unroll
      for (int i = 0; i < 4; ++i) a4[i] = *(const float4*)(sQ + (r0 + i) * 68 + dd);
#pragma unroll
      for (int e = 0; e < 4; ++e) b4[e] = *(const float4*)(sKT + (dd + e) * 68 + c0);
      gemm4x4(acc, a4, b4);
    }

#pragma unroll
    for (int i = 0; i < 4; ++i) {
      const int4 mv = *(const int4*)(mp + (size_t)(r0 + i) * L_ + kt * 64 + c0);
      const float s0_ = (mv.x == 0) ? -1e12f : acc[i][0] * 0.125f;
      const float s1_ = (mv.y == 0) ? -1e12f : acc[i][1] * 0.125f;
      const float s2_ = (mv.z == 0) ? -1e12f : acc[i][2] * 0.125f;
      const float s3_ = (mv.w == 0) ? -1e12f : acc[i][3] * 0.125f;
      float mt = fmaxf(fmaxf(s0_, s1_), fmaxf(s2_, s3_));
#pragma unroll
      for (int off = 1; off < 16; off <<= 1) mt = fmaxf(mt, __shfl_xor(mt, off));
      const float mnew = fmaxf(mrun[i], mt);
      const float p0 = expf(s0_ - mnew);
      const float p1 = expf(s1_ - mnew);
      const float p2 = expf(s2_ - mnew);
      const float p3 = expf(s3_ - mnew);
      float pt = p0 + p1 + p2 + p3;
#pragma unroll
      for (int off = 1; off < 16; off <<= 1) pt += __shfl_xor(pt, off);
      const float scale = expf(mrun[i] - mnew);
      mrun[i] = mnew;
      lrun[i] = lrun[i] * scale + pt;
      o_[i][0] *= scale; o_[i][1] *= scale; o_[i][2] *= scale; o_[i][3] *= scale;
      float4 pw; pw.x = p0; pw.y = p1; pw.z = p2; pw.w = p3;
      *(float4*)(sP + (r0 + i) * 68 + c0) = pw;
    }
    __syncthreads();

#pragma unroll 4
    for (int cc = 0; cc < 64; cc += 4) {
      float4 a4[4], b4[4];
#pragma unroll
      for (int i = 0; i < 4; ++i) a4[i] = *(const float4*)(sP + (r0 + i) * 68 + cc);
#pragma unroll
      for (int e = 0; e < 4; ++e) b4[e] = *(const float4*)(sV + (cc + e) * 68 + c0);
      gemm4x4(o_, a4, b4);
    }
    __syncthreads();
  }

#pragma unroll
  for (int i = 0; i < 4; ++i) {
    const float inv = 1.f / lrun[i];
    float4 r_;
    r_.x = o_[i][0] * inv; r_.y = o_[i][1] * inv;
    r_.z = o_[i][2] * inv; r_.w = o_[i][3] * inv;
    *(float4*)(op + (size_t)(r0 + i) * DK_ + c0) = r_;
  }
}

// ---------------- GRU (heads 8..23), bf16 MFMA ------------------------------
// grid (L/128, NG*LH=16, B), block 512 (8 waves). Wave w owns sequences
// 16w..16w+15 of a 128-seq l-tile; h state lives f32 in MFMA C-fragments.
// Per step: gh = (h_hi + h_lo) * W_hh^T via 2-term bf16 MFMA (h split keeps
// ~16-bit mantissa on the recurrent path); gates elementwise in C-frag space
// (r/z/n are N-tiles t, t+4, t+8 -> identical lane layout). h round-trips
// LDS as bf16 hi/lo for the C->A transpose; wave-private => no barriers in
// the 9-step loop.
// MFMA 16x16x32 layouts: A: m=lane&15, k=(lane>>4)*8+i ; B: n=lane&15,
// k=(lane>>4)*8+i ; C/D: col=lane&15, row=(lane>>4)*4+reg  [m89].
// W_hh LDS [192][64]bf16 row-major 128B rows, byte^=((row&7)<<4) swizzle (G4).
__global__ __launch_bounds__(512) void gru_kernel(
    const float* __restrict__ value, const float* __restrict__ wih_g,
    const float* __restrict__ whh_g, const float* __restrict__ bih_g,
    const float* __restrict__ bhh_g, float* __restrict__ out)
{
  extern __shared__ char smc[];
  char*           sW   = smc + GRU_W_OFF;                    // W_hh bf16 swz
  unsigned short* sXG  = (unsigned short*)(smc + GRU_XG_OFF); // [144][196] bf16
  char*           sHB  = smc + GRU_HB_OFF;                   // per-wave h hi/lo
  float*          sBih = (float*)(smc + GRU_BIH_OFF);        // [192]

  const int tid  = threadIdx.x;
  const int l0   = blockIdx.x * 128;
  const int gset = blockIdx.y >> 2;
  const int vh   = blockIdx.y & 3;
  const int b    = blockIdx.z;

  const float* vp   = value + (((size_t)b * H_ + GH_ + vh) * L_) * DK_;
  const float* wih  = wih_g + (size_t)gset * 192 * DK_;
  const float* whh  = whh_g + (size_t)gset * 192 * DK_;
  const float* bihp = bih_g + gset * 192;
  const float* bhhp = bhh_g + gset * 192;

  // ---- staging: b_ih, zero h-buffers, W_hh -> bf16 swizzled LDS ----
  if (tid < 192) sBih[tid] = bihp[tid];
#pragma unroll
  for (int k2 = 0; k2 < 4; ++k2) {
    uint4 z; z.x = 0u; z.y = 0u; z.z = 0u; z.w = 0u;
    *(uint4*)(sHB + ((size_t)tid + 512 * k2) * 16) = z;
  }
  for (int cid = tid; cid < 1536; cid += 512) {   // 192 rows * 8 chunks(16B)
    const int row = cid >> 3, ch = cid & 7;
    const float* wp = whh + row * 64 + ch * 8;
    const float4 w0 = *(const float4*)wp;
    const float4 w1 = *(const float4*)(wp + 4);
    uint4 pk;
    pk.x = (unsigned)f2bf(w0.x) | ((unsigned)f2bf(w0.y) << 16);
    pk.y = (unsigned)f2bf(w0.z) | ((unsigned)f2bf(w0.w) << 16);
    pk.z = (unsigned)f2bf(w1.x) | ((unsigned)f2bf(w1.y) << 16);
    pk.w = (unsigned)f2bf(w1.z) | ((unsigned)f2bf(w1.w) << 16);
    *(uint4*)(sW + ((row * 128 + ch * 16) ^ ((row & 7) << 4))) = pk;
  }
  __syncthreads();

  const int w  = tid >> 6;        // wave id 0..7
  const int ln = tid & 63;
  const int lg = ln >> 4;         // lane group 0..3
  const int c  = ln & 15;         // lane col 0..15

  // ---- phase 1: XG[pos][j] = v[pos]·W_ih[j] + b_ih[j], pos in [0,144) ----
  // 9 M-tiles x 12 N-tiles, wave-strided; A (v) and B (W_ih) from global.
  for (int t = w; t < 108; t += 8) {
    const int Mt = t / 12, Nt = t - Mt * 12;
    const int row = l0 + Mt * 16 + c;
    const bool valid = row < L_;
    const float* va = vp + (size_t)row * 64 + lg * 8;
    float4 z4; z4.x = 0.f; z4.y = 0.f; z4.z = 0.f; z4.w = 0.f;
    const float4 a00 = valid ? *(const float4*)(va)      : z4;
    const float4 a01 = valid ? *(const float4*)(va + 4)  : z4;
    const float4 a10 = valid ? *(const float4*)(va + 32) : z4;
    const float4 a11 = valid ? *(const float4*)(va + 36) : z4;
    const float* wb = wih + (size_t)(Nt * 16 + c) * 64 + lg * 8;
    const float4 b00 = *(const float4*)(wb);
    const float4 b01 = *(const float4*)(wb + 4);
    const float4 b10 = *(const float4*)(wb + 32);
    const float4 b11 = *(const float4*)(wb + 36);
    f32x4 acc = {0.f, 0.f, 0.f, 0.f};
    acc = MFMA_BF16(pack8(a00, a01), pack8(b00, b01), acc);
    acc = MFMA_BF16(pack8(a10, a11), pack8(b10, b11), acc);
    const float bias = sBih[Nt * 16 + c];
    const int pos0 = Mt * 16 + lg * 4;
    const int jj = Nt * 16 + c;
#pragma unroll
    for (int r = 0; r < 4; ++r)
      sXG[(pos0 + r) * 196 + jj] = f2bf(acc[r] + bias);
  }
  __syncthreads();

  // ---- recurrence: 9 steps, no barriers (wave-private h buffers) ----
  char* hbH = sHB + w * 4096;
  char* hbL = hbH + 2048;

  float bhh[12];
#pragma unroll
  for (int n = 0; n < 12; ++n) bhh[n] = bhhp[n * 16 + c];

  f32x4 hfr[4];
#pragma unroll
  for (int t = 0; t < 4; ++t) { hfr[t][0] = 0.f; hfr[t][1] = 0.f; hfr[t][2] = 0.f; hfr[t][3] = 0.f; }

  const int seqB = w * 16;

  for (int ts = 0; ts < WS_; ++ts) {
    // A-frags: previous h (hi/lo) from wave-private LDS
    short8 ahi[2], alo[2];
#pragma unroll
    for (int kt = 0; kt < 2; ++kt) {
      const int ao = (c * 128 + kt * 64 + lg * 16) ^ ((c & 7) << 4);
      ahi[kt] = __builtin_bit_cast(short8, *(const uint4*)(hbH + ao));
      alo[kt] = __builtin_bit_cast(short8, *(const uint4*)(hbL + ao));
    }
    // gh = (h_hi + h_lo) * W_hh^T
    f32x4 acc[12];
#pragma unroll
    for (int n = 0; n < 12; ++n) {
      acc[n][0] = 0.f; acc[n][1] = 0.f; acc[n][2] = 0.f; acc[n][3] = 0.f;
#pragma unroll
      for (int kt = 0; kt < 2; ++kt) {
        const int wo = ((n * 16 + c) * 128 + kt * 64 + lg * 16) ^ ((c & 7) << 4);
        const short8 bw = __builtin_bit_cast(short8, *(const uint4*)(sW + wo));
        acc[n] = MFMA_BF16(ahi[kt], bw, acc[n]);
        acc[n] = MFMA_BF16(alo[kt], bw, acc[n]);
      }
    }
    // gates + h update, elementwise in C-fragment space
#pragma unroll
    for (int t = 0; t < 4; ++t) {
#pragma unroll
      for (int r = 0; r < 4; ++r) {
        const int pos = seqB + lg * 4 + r + ts;
        const int d = c + 16 * t;
        const float xr = bf2f(sXG[pos * 196 + d]);
        const float xz = bf2f(sXG[pos * 196 + 64 + d]);
        const float xn = bf2f(sXG[pos * 196 + 128 + d]);
        const float ghr = acc[t][r] + bhh[t];
        const float ghz = acc[t + 4][r] + bhh[t + 4];
        const float ghn = acc[t + 8][r] + bhh[t + 8];
        const float rr = __builtin_amdgcn_rcpf(1.f + __expf(-(xr + ghr)));
        const float zz = __builtin_amdgcn_rcpf(1.f + __expf(-(xz + ghz)));
        const float e2 = __expf(2.f * (xn + rr * ghn));
        const float nn = 1.f - 2.f * __builtin_amdgcn_rcpf(1.f + e2);
        float h = hfr[t][r];
        h = (1.f - zz) * nn + zz * h;
        hfr[t][r] = h;
        // write back bf16 hi/lo for next step's A-frags (swizzled rows)
        const int sl = lg * 4 + r;
        const int hb = (sl * 128 + d * 2) ^ ((sl & 7) << 4);
        const unsigned short hhi = f2bf(h);
        *(unsigned short*)(hbH + hb) = hhi;
        *(unsigned short*)(hbL + hb) = f2bf(h - bf2f(hhi));
      }
    }
  }

  // ---- write final hidden ----
  float* op = out + (((size_t)b * 24 + (GH_ + gset * 4 + vh)) * L_ + l0) * DK_;
#pragma unroll
  for (int t = 0; t < 4; ++t)
#pragma unroll
    for (int r = 0; r < 4; ++r)
      op[(size_t)(seqB + lg * 4 + r) * 64 + c + 16 * t] = hfr[t][r];
}

extern "C" void kernel_launch(void* const* d_in, const int* in_sizes, int n_in,
                              void* d_out, int out_size, void* d_ws, size_t ws_size,
                              hipStream_t stream) {
  (void)in_sizes; (void)n_in; (void)d_ws; (void)ws_size; (void)out_size;
  const float* q   = (const float*)d_in[0];
  const float* k   = (const float*)d_in[1];
  const float* v   = (const float*)d_in[2];
  const int*   msk = (const int*)d_in[3];
  const float* wih = (const float*)d_in[4];
  const float* whh = (const float*)d_in[5];
  const float* bih = (const float*)d_in[6];
  const float* bhh = (const float*)d_in[7];
  float* out = (float*)d_out;

  (void)hipFuncSetAttribute((const void*)attn_kernel,
                            hipFuncAttributeMaxDynamicSharedMemorySize, ATTN_LDS_BYTES);
  (void)hipFuncSetAttribute((const void*)gru_kernel,
                            hipFuncAttributeMaxDynamicSharedMemorySize, GRU_LDS_BYTES);

  attn_kernel<<<dim3(L_ / 64, GH_, B_), dim3(256), ATTN_LDS_BYTES, stream>>>(q, k, v, msk, out);
  gru_kernel<<<dim3(L_ / 128, 16, B_), dim3(512), GRU_LDS_BYTES, stream>>>(v, wih, whh, bih, bhh, out);
}

// Round 4
// 342.215 us; speedup vs baseline: 2.1007x; 1.2616x over previous
//
#include <hip/hip_runtime.h>

// Problem constants
#define B_  4
#define H_  12
#define L_  1024
#define DK_ 64
#define GH_ 8      // global attention heads
#define WS_ 9      // gru window steps (INIT_VAL+1)

// attention LDS: sK [64][64]bf16 swz + sVT [64][64]bf16 swz + sP 4 waves x [16][64]bf16
#define ATTN_LDS_BYTES (3 * 64 * 64 * 2)   // 24,576
// GRU LDS: W_hh bf16 [192][64] swz (24576) + XG bf16 [144][196] (56448)
//        + h-buf 8 waves * (hi 2048 + lo 2048) (32768) + b_ih f32 [192] (768)
#define GRU_W_OFF   0
#define GRU_XG_OFF  24576
#define GRU_HB_OFF  81024
#define GRU_BIH_OFF 113792
#define GRU_LDS_BYTES 114560

#define MB_WORDS (B_ * L_ * 16)            // 65,536 u64 words = 512 KB

typedef __attribute__((ext_vector_type(8))) short short8;
typedef __attribute__((ext_vector_type(4))) float f32x4;

#define MFMA_BF16(a, b, c) __builtin_amdgcn_mfma_f32_16x16x32_bf16((a), (b), (c), 0, 0, 0)

__device__ __forceinline__ unsigned short f2bf(float f) {  // f32 -> bf16 bits, RNE
  unsigned int u = __builtin_bit_cast(unsigned int, f);
  u += 0x7fffu + ((u >> 16) & 1u);
  return (unsigned short)(u >> 16);
}
__device__ __forceinline__ float bf2f(unsigned short s) {  // bf16 bits -> f32 (exact)
  return __builtin_bit_cast(float, ((unsigned int)s) << 16);
}
__device__ __forceinline__ short8 pack8(const float4 a, const float4 b) {
  short8 r;
  r[0] = (short)f2bf(a.x); r[1] = (short)f2bf(a.y);
  r[2] = (short)f2bf(a.z); r[3] = (short)f2bf(a.w);
  r[4] = (short)f2bf(b.x); r[5] = (short)f2bf(b.y);
  r[6] = (short)f2bf(b.z); r[7] = (short)f2bf(b.w);
  return r;
}
__device__ __forceinline__ uint4 packrow16(const float4 a, const float4 b) {
  uint4 r;
  r.x = (unsigned)f2bf(a.x) | ((unsigned)f2bf(a.y) << 16);
  r.y = (unsigned)f2bf(a.z) | ((unsigned)f2bf(a.w) << 16);
  r.z = (unsigned)f2bf(b.x) | ((unsigned)f2bf(b.y) << 16);
  r.w = (unsigned)f2bf(b.z) | ((unsigned)f2bf(b.w) << 16);
  return r;
}

// ---------------- mask bit-pack: int32 [B][L][L] -> u64 bits [B*L][16] -----
__global__ __launch_bounds__(256) void maskpack_kernel(
    const int* __restrict__ mask, unsigned long long* __restrict__ mb)
{
  const int idx = blockIdx.x * 256 + threadIdx.x;   // word id, 0..65535
  const int* src = mask + (size_t)idx * 64;
  unsigned long long bits = 0ull;
#pragma unroll
  for (int i = 0; i < 16; ++i) {
    const int4 m4 = *(const int4*)(src + i * 4);
    if (m4.x) bits |= 1ull << (i * 4 + 0);
    if (m4.y) bits |= 1ull << (i * 4 + 1);
    if (m4.z) bits |= 1ull << (i * 4 + 2);
    if (m4.w) bits |= 1ull << (i * 4 + 3);
  }
  mb[idx] = bits;
}

// ---------------- Global attention (heads 0..7), bf16 MFMA flash -----------
// grid (L/64, 8, B), block 256 (4 waves). Wave w owns q-rows q0+16w..+15.
// Per 64-col k-tile: S = Q K^T (8 MFMA), mask+online softmax in C-frag space,
// P -> wave-private LDS (bf16), O += P V (8 MFMA). K row-major and V
// TRANSPOSED (VT[d][kcol]) staged bf16 in LDS, XOR swizzle byte^=((row&7)<<4)
// (same pattern that measured 0 bank conflicts in gru_kernel).
// MFMA 16x16x32 layouts [m89]: A/B: m|n=lane&15, k=(lane>>4)*8+i;
// C/D: col=lane&15, row=(lane>>4)*4+reg.
__global__ __launch_bounds__(256) void attn_kernel(
    const float* __restrict__ q, const float* __restrict__ k,
    const float* __restrict__ v, const int* __restrict__ mask,
    const unsigned long long* __restrict__ mb, const int use_bits,
    float* __restrict__ out)
{
  extern __shared__ char smc[];
  char* sK  = smc;            // [64][64] bf16, swizzled rows (128B)
  char* sVT = smc + 8192;     // [64][64] bf16: VT[d][kcol], swizzled rows
  char* sP  = smc + 16384;    // wave w: [16][64] bf16 at +2048*w

  const int tid = threadIdx.x;
  const int q0 = blockIdx.x * 64;
  const int h  = blockIdx.y;
  const int b  = blockIdx.z;

  const int w  = tid >> 6;
  const int ln = tid & 63;
  const int lg = ln >> 4;        // lane group 0..3
  const int c  = ln & 15;        // lane col 0..15

  const size_t hbase = ((size_t)b * H_ + h) * L_ * DK_;
  const float* kp = k + hbase;
  const float* vp = v + hbase;
  const int*   mp = mask + (size_t)b * L_ * L_;
  const unsigned long long* mbp = mb + (size_t)b * L_ * 16;

  // Q A-fragments in registers: rows q0 + w*16 + c, d = kt*32 + lg*8 + i
  short8 qa[2];
  {
    const float* qrow = q + hbase + (size_t)(q0 + w * 16 + c) * DK_ + lg * 8;
#pragma unroll
    for (int kt = 0; kt < 2; ++kt) {
      const float4 f0 = *(const float4*)(qrow + kt * 32);
      const float4 f1 = *(const float4*)(qrow + kt * 32 + 4);
      qa[kt] = pack8(f0, f1);
    }
  }

  char* sPw = sP + w * 2048;

  f32x4 o_[4];
#pragma unroll
  for (int nt = 0; nt < 4; ++nt) { o_[nt][0] = 0.f; o_[nt][1] = 0.f; o_[nt][2] = 0.f; o_[nt][3] = 0.f; }
  float mrun[4], lrun[4];
#pragma unroll
  for (int r = 0; r < 4; ++r) { mrun[r] = -1e30f; lrun[r] = 0.f; }

  // staging role: row rr, 16-col chunk c16
  const int rr  = tid >> 2;
  const int c16 = (tid & 3) << 4;

  for (int kt0 = 0; kt0 < 16; ++kt0) {
    // ---- stage K (row-major bf16) and V^T (transposed bf16), swizzled ----
    {
      const float* ksrc = kp + (size_t)(kt0 * 64 + rr) * DK_ + c16;
      const float4 k0 = *(const float4*)(ksrc);
      const float4 k1 = *(const float4*)(ksrc + 4);
      const float4 k2 = *(const float4*)(ksrc + 8);
      const float4 k3 = *(const float4*)(ksrc + 12);
      const int kb = rr * 128 + c16 * 2;
      const int sw = (rr & 7) << 4;
      *(uint4*)(sK + ((kb) ^ sw))      = packrow16(k0, k1);
      *(uint4*)(sK + ((kb + 16) ^ sw)) = packrow16(k2, k3);

      const float* vsrc = vp + (size_t)(kt0 * 64 + rr) * DK_ + c16;
      const float4 v0 = *(const float4*)(vsrc);
      const float4 v1 = *(const float4*)(vsrc + 4);
      const float4 v2 = *(const float4*)(vsrc + 8);
      const float4 v3 = *(const float4*)(vsrc + 12);
      const float vv[16] = {v0.x, v0.y, v0.z, v0.w, v1.x, v1.y, v1.z, v1.w,
                            v2.x, v2.y, v2.z, v2.w, v3.x, v3.y, v3.z, v3.w};
#pragma unroll
      for (int j = 0; j < 16; ++j) {
        const int d = c16 + j;
        *(unsigned short*)(sVT + ((d * 128 + rr * 2) ^ ((d & 7) << 4))) = f2bf(vv[j]);
      }
    }
    __syncthreads();

    // ---- S = Q K^T : 4 N-tiles x 2 K-chunks ----
    f32x4 acc[4];
#pragma unroll
    for (int nt = 0; nt < 4; ++nt) {
      acc[nt][0] = 0.f; acc[nt][1] = 0.f; acc[nt][2] = 0.f; acc[nt][3] = 0.f;
#pragma unroll
      for (int kt = 0; kt < 2; ++kt) {
        const int off = (((nt * 16 + c) * 128 + kt * 64 + lg * 16) ^ ((c & 7) << 4));
        const short8 bk = __builtin_bit_cast(short8, *(const uint4*)(sK + off));
        acc[nt] = MFMA_BF16(qa[kt], bk, acc[nt]);
      }
    }

    // ---- mask + online softmax (rows lg*4+r; 16 c-lanes share a row) ----
#pragma unroll
    for (int r = 0; r < 4; ++r) {
      const int qr = q0 + w * 16 + lg * 4 + r;
      unsigned long long mword = 0ull;
      int mi0 = 0, mi1 = 0, mi2 = 0, mi3 = 0;
      if (use_bits) {
        mword = mbp[(size_t)qr * 16 + kt0];
      } else {
        const int* mrow = mp + (size_t)qr * L_ + kt0 * 64 + c;
        mi0 = mrow[0]; mi1 = mrow[16]; mi2 = mrow[32]; mi3 = mrow[48];
      }
      const bool k0_ = use_bits ? ((mword >> (c)) & 1ull)      : (mi0 != 0);
      const bool k1_ = use_bits ? ((mword >> (16 + c)) & 1ull) : (mi1 != 0);
      const bool k2_ = use_bits ? ((mword >> (32 + c)) & 1ull) : (mi2 != 0);
      const bool k3_ = use_bits ? ((mword >> (48 + c)) & 1ull) : (mi3 != 0);
      const float s0_ = k0_ ? acc[0][r] * 0.125f : -1e12f;
      const float s1_ = k1_ ? acc[1][r] * 0.125f : -1e12f;
      const float s2_ = k2_ ? acc[2][r] * 0.125f : -1e12f;
      const float s3_ = k3_ ? acc[3][r] * 0.125f : -1e12f;
      float mt = fmaxf(fmaxf(s0_, s1_), fmaxf(s2_, s3_));
#pragma unroll
      for (int off = 1; off < 16; off <<= 1) mt = fmaxf(mt, __shfl_xor(mt, off));
      const float mnew = fmaxf(mrun[r], mt);
      const float p0 = __expf(s0_ - mnew);
      const float p1 = __expf(s1_ - mnew);
      const float p2 = __expf(s2_ - mnew);
      const float p3 = __expf(s3_ - mnew);
      float pt = p0 + p1 + p2 + p3;
#pragma unroll
      for (int off = 1; off < 16; off <<= 1) pt += __shfl_xor(pt, off);
      const float scale = __expf(mrun[r] - mnew);
      mrun[r] = mnew;
      lrun[r] = lrun[r] * scale + pt;
      o_[0][r] *= scale; o_[1][r] *= scale; o_[2][r] *= scale; o_[3][r] *= scale;
      // write P row (wave-private LDS)
      const int prow = lg * 4 + r;
      const int pb = prow * 128;
      const int psw = (prow & 7) << 4;
      *(unsigned short*)(sPw + ((pb + (c * 2)) ^ psw))       = f2bf(p0);
      *(unsigned short*)(sPw + ((pb + (16 + c) * 2) ^ psw))  = f2bf(p1);
      *(unsigned short*)(sPw + ((pb + (32 + c) * 2) ^ psw))  = f2bf(p2);
      *(unsigned short*)(sPw + ((pb + (48 + c) * 2) ^ psw))  = f2bf(p3);
    }

    // ---- O += P V  (A = P from wave-private LDS, B = V^T) ----
#pragma unroll
    for (int kt = 0; kt < 2; ++kt) {
      const int aoff = ((c * 128 + kt * 64 + lg * 16) ^ ((c & 7) << 4));
      const short8 pa = __builtin_bit_cast(short8, *(const uint4*)(sPw + aoff));
#pragma unroll
      for (int nt = 0; nt < 4; ++nt) {
        const int boff = (((nt * 16 + c) * 128 + kt * 64 + lg * 16) ^ ((c & 7) << 4));
        const short8 bv = __builtin_bit_cast(short8, *(const uint4*)(sVT + boff));
        o_[nt] = MFMA_BF16(pa, bv, o_[nt]);
      }
    }
    __syncthreads();
  }

  // ---- finalize: divide by l, store f32 ----
  float* op = out + (((size_t)b * 24 + h) * L_ + q0 + w * 16) * DK_;
#pragma unroll
  for (int r = 0; r < 4; ++r) {
    const float inv = 1.f / lrun[r];
#pragma unroll
    for (int nt = 0; nt < 4; ++nt)
      op[(size_t)(lg * 4 + r) * DK_ + nt * 16 + c] = o_[nt][r] * inv;
  }
}

// ---------------- GRU (heads 8..23), bf16 MFMA (unchanged) ------------------
__global__ __launch_bounds__(512) void gru_kernel(
    const float* __restrict__ value, const float* __restrict__ wih_g,
    const float* __restrict__ whh_g, const float* __restrict__ bih_g,
    const float* __restrict__ bhh_g, float* __restrict__ out)
{
  extern __shared__ char smc[];
  char*           sW   = smc + GRU_W_OFF;                     // W_hh bf16 swz
  unsigned short* sXG  = (unsigned short*)(smc + GRU_XG_OFF); // [144][196] bf16
  char*           sHB  = smc + GRU_HB_OFF;                    // per-wave h hi/lo
  float*          sBih = (float*)(smc + GRU_BIH_OFF);         // [192]

  const int tid  = threadIdx.x;
  const int l0   = blockIdx.x * 128;
  const int gset = blockIdx.y >> 2;
  const int vh   = blockIdx.y & 3;
  const int b    = blockIdx.z;

  const float* vp   = value + (((size_t)b * H_ + GH_ + vh) * L_) * DK_;
  const float* wih  = wih_g + (size_t)gset * 192 * DK_;
  const float* whh  = whh_g + (size_t)gset * 192 * DK_;
  const float* bihp = bih_g + gset * 192;
  const float* bhhp = bhh_g + gset * 192;

  if (tid < 192) sBih[tid] = bihp[tid];
#pragma unroll
  for (int k2 = 0; k2 < 4; ++k2) {
    uint4 z; z.x = 0u; z.y = 0u; z.z = 0u; z.w = 0u;
    *(uint4*)(sHB + ((size_t)tid + 512 * k2) * 16) = z;
  }
  for (int cid = tid; cid < 1536; cid += 512) {   // 192 rows * 8 chunks(16B)
    const int row = cid >> 3, ch = cid & 7;
    const float* wp = whh + row * 64 + ch * 8;
    const float4 w0 = *(const float4*)wp;
    const float4 w1 = *(const float4*)(wp + 4);
    *(uint4*)(sW + ((row * 128 + ch * 16) ^ ((row & 7) << 4))) = packrow16(w0, w1);
  }
  __syncthreads();

  const int w  = tid >> 6;
  const int ln = tid & 63;
  const int lg = ln >> 4;
  const int c  = ln & 15;

  for (int t = w; t < 108; t += 8) {
    const int Mt = t / 12, Nt = t - Mt * 12;
    const int row = l0 + Mt * 16 + c;
    const bool valid = row < L_;
    const float* va = vp + (size_t)row * 64 + lg * 8;
    float4 z4; z4.x = 0.f; z4.y = 0.f; z4.z = 0.f; z4.w = 0.f;
    const float4 a00 = valid ? *(const float4*)(va)      : z4;
    const float4 a01 = valid ? *(const float4*)(va + 4)  : z4;
    const float4 a10 = valid ? *(const float4*)(va + 32) : z4;
    const float4 a11 = valid ? *(const float4*)(va + 36) : z4;
    const float* wb = wih + (size_t)(Nt * 16 + c) * 64 + lg * 8;
    const float4 b00 = *(const float4*)(wb);
    const float4 b01 = *(const float4*)(wb + 4);
    const float4 b10 = *(const float4*)(wb + 32);
    const float4 b11 = *(const float4*)(wb + 36);
    f32x4 acc = {0.f, 0.f, 0.f, 0.f};
    acc = MFMA_BF16(pack8(a00, a01), pack8(b00, b01), acc);
    acc = MFMA_BF16(pack8(a10, a11), pack8(b10, b11), acc);
    const float bias = sBih[Nt * 16 + c];
    const int pos0 = Mt * 16 + lg * 4;
    const int jj = Nt * 16 + c;
#pragma unroll
    for (int r = 0; r < 4; ++r)
      sXG[(pos0 + r) * 196 + jj] = f2bf(acc[r] + bias);
  }
  __syncthreads();

  char* hbH = sHB + w * 4096;
  char* hbL = hbH + 2048;

  float bhh[12];
#pragma unroll
  for (int n = 0; n < 12; ++n) bhh[n] = bhhp[n * 16 + c];

  f32x4 hfr[4];
#pragma unroll
  for (int t = 0; t < 4; ++t) { hfr[t][0] = 0.f; hfr[t][1] = 0.f; hfr[t][2] = 0.f; hfr[t][3] = 0.f; }

  const int seqB = w * 16;

  for (int ts = 0; ts < WS_; ++ts) {
    short8 ahi[2], alo[2];
#pragma unroll
    for (int kt = 0; kt < 2; ++kt) {
      const int ao = (c * 128 + kt * 64 + lg * 16) ^ ((c & 7) << 4);
      ahi[kt] = __builtin_bit_cast(short8, *(const uint4*)(hbH + ao));
      alo[kt] = __builtin_bit_cast(short8, *(const uint4*)(hbL + ao));
    }
    f32x4 acc[12];
#pragma unroll
    for (int n = 0; n < 12; ++n) {
      acc[n][0] = 0.f; acc[n][1] = 0.f; acc[n][2] = 0.f; acc[n][3] = 0.f;
#pragma unroll
      for (int kt = 0; kt < 2; ++kt) {
        const int wo = ((n * 16 + c) * 128 + kt * 64 + lg * 16) ^ ((c & 7) << 4);
        const short8 bw = __builtin_bit_cast(short8, *(const uint4*)(sW + wo));
        acc[n] = MFMA_BF16(ahi[kt], bw, acc[n]);
        acc[n] = MFMA_BF16(alo[kt], bw, acc[n]);
      }
    }
#pragma unroll
    for (int t = 0; t < 4; ++t) {
#pragma unroll
      for (int r = 0; r < 4; ++r) {
        const int pos = seqB + lg * 4 + r + ts;
        const int d = c + 16 * t;
        const float xr = bf2f(sXG[pos * 196 + d]);
        const float xz = bf2f(sXG[pos * 196 + 64 + d]);
        const float xn = bf2f(sXG[pos * 196 + 128 + d]);
        const float ghr = acc[t][r] + bhh[t];
        const float ghz = acc[t + 4][r] + bhh[t + 4];
        const float ghn = acc[t + 8][r] + bhh[t + 8];
        const float rr = __builtin_amdgcn_rcpf(1.f + __expf(-(xr + ghr)));
        const float zz = __builtin_amdgcn_rcpf(1.f + __expf(-(xz + ghz)));
        const float e2 = __expf(2.f * (xn + rr * ghn));
        const float nn = 1.f - 2.f * __builtin_amdgcn_rcpf(1.f + e2);
        float h = hfr[t][r];
        h = (1.f - zz) * nn + zz * h;
        hfr[t][r] = h;
        const int sl = lg * 4 + r;
        const int hb = (sl * 128 + d * 2) ^ ((sl & 7) << 4);
        const unsigned short hhi = f2bf(h);
        *(unsigned short*)(hbH + hb) = hhi;
        *(unsigned short*)(hbL + hb) = f2bf(h - bf2f(hhi));
      }
    }
  }

  float* op = out + (((size_t)b * 24 + (GH_ + gset * 4 + vh)) * L_ + l0) * DK_;
#pragma unroll
  for (int t = 0; t < 4; ++t)
#pragma unroll
    for (int r = 0; r < 4; ++r)
      op[(size_t)(seqB + lg * 4 + r) * 64 + c + 16 * t] = hfr[t][r];
}

extern "C" void kernel_launch(void* const* d_in, const int* in_sizes, int n_in,
                              void* d_out, int out_size, void* d_ws, size_t ws_size,
                              hipStream_t stream) {
  (void)in_sizes; (void)n_in; (void)out_size;
  const float* q   = (const float*)d_in[0];
  const float* k   = (const float*)d_in[1];
  const float* v   = (const float*)d_in[2];
  const int*   msk = (const int*)d_in[3];
  const float* wih = (const float*)d_in[4];
  const float* whh = (const float*)d_in[5];
  const float* bih = (const float*)d_in[6];
  const float* bhh = (const float*)d_in[7];
  float* out = (float*)d_out;

  const int use_bits = (ws_size >= (size_t)MB_WORDS * 8) ? 1 : 0;
  unsigned long long* mb = (unsigned long long*)d_ws;

  (void)hipFuncSetAttribute((const void*)gru_kernel,
                            hipFuncAttributeMaxDynamicSharedMemorySize, GRU_LDS_BYTES);

  if (use_bits)
    maskpack_kernel<<<dim3(MB_WORDS / 256), dim3(256), 0, stream>>>(msk, mb);
  attn_kernel<<<dim3(L_ / 64, GH_, B_), dim3(256), ATTN_LDS_BYTES, stream>>>(
      q, k, v, msk, mb, use_bits, out);
  gru_kernel<<<dim3(L_ / 128, 16, B_), dim3(512), GRU_LDS_BYTES, stream>>>(
      v, wih, whh, bih, bhh, out);
}

// Round 7
// 325.904 us; speedup vs baseline: 2.2059x; 1.0500x over previous
//
#include <hip/hip_runtime.h>

// Problem constants
#define B_  4
#define H_  12
#define L_  1024
#define DK_ 64
#define GH_ 8      // global attention heads
#define WS_ 9      // gru window steps (INIT_VAL+1)

// attention LDS: sK [64][64]bf16 swz + sVT [64][64]bf16 swz + sP 4 waves x [16][64]bf16
#define ATTN_LDS_BYTES (3 * 64 * 64 * 2)   // 24,576
// GRU LDS: W_hh bf16 [192][64] swz (24576) + XGT bf16 [192][148] stride 296B (56832)
//        + h-buf 8 waves * (hi 2048 + lo 2048) (32768) + b_ih f32 [192] (768)
#define GRU_W_OFF    0
#define GRU_XGT_OFF  24576
#define GRU_HB_OFF   81408
#define GRU_BIH_OFF  114176
#define GRU_LDS_BYTES 114944
#define XGT_STRIDE   296   // bytes per j-row (148 u16); 74 dwords -> 16-lane b64 covers all 32 banks

#define MB_WORDS (B_ * L_ * 16)            // 65,536 u64 words = 512 KB

typedef __attribute__((ext_vector_type(8))) short short8;
typedef __attribute__((ext_vector_type(4))) float f32x4;

#define MFMA_BF16(a, b, c) __builtin_amdgcn_mfma_f32_16x16x32_bf16((a), (b), (c), 0, 0, 0)

__device__ __forceinline__ unsigned short f2bf(float f) {  // f32 -> bf16 bits, RNE
  unsigned int u = __builtin_bit_cast(unsigned int, f);
  u += 0x7fffu + ((u >> 16) & 1u);
  return (unsigned short)(u >> 16);
}
__device__ __forceinline__ float bf2f(unsigned short s) {  // bf16 bits -> f32 (exact)
  return __builtin_bit_cast(float, ((unsigned int)s) << 16);
}
__device__ __forceinline__ short8 pack8(const float4 a, const float4 b) {
  short8 r;
  r[0] = (short)f2bf(a.x); r[1] = (short)f2bf(a.y);
  r[2] = (short)f2bf(a.z); r[3] = (short)f2bf(a.w);
  r[4] = (short)f2bf(b.x); r[5] = (short)f2bf(b.y);
  r[6] = (short)f2bf(b.z); r[7] = (short)f2bf(b.w);
  return r;
}
__device__ __forceinline__ uint4 packrow16(const float4 a, const float4 b) {
  uint4 r;
  r.x = (unsigned)f2bf(a.x) | ((unsigned)f2bf(a.y) << 16);
  r.y = (unsigned)f2bf(a.z) | ((unsigned)f2bf(a.w) << 16);
  r.z = (unsigned)f2bf(b.x) | ((unsigned)f2bf(b.y) << 16);
  r.w = (unsigned)f2bf(b.z) | ((unsigned)f2bf(b.w) << 16);
  return r;
}
// extract bf16 #wi (compile-time wi, 0..11) from a 3x uint2 window as f32
__device__ __forceinline__ float xg_get(const uint2* xg3, const int wi) {
  const unsigned d = (wi & 2) ? xg3[wi >> 2].y : xg3[wi >> 2].x;
  return (wi & 1) ? __builtin_bit_cast(float, d & 0xffff0000u)
                  : __builtin_bit_cast(float, d << 16);
}

// ---------------- mask bit-pack: int32 [B][L][L] -> u64 bits [B*L][16] -----
__global__ __launch_bounds__(256) void maskpack_kernel(
    const int* __restrict__ mask, unsigned long long* __restrict__ mb)
{
  const int idx = blockIdx.x * 256 + threadIdx.x;   // word id, 0..65535
  const int* src = mask + (size_t)idx * 64;
  unsigned long long bits = 0ull;
#pragma unroll
  for (int i = 0; i < 16; ++i) {
    const int4 m4 = *(const int4*)(src + i * 4);
    if (m4.x) bits |= 1ull << (i * 4 + 0);
    if (m4.y) bits |= 1ull << (i * 4 + 1);
    if (m4.z) bits |= 1ull << (i * 4 + 2);
    if (m4.w) bits |= 1ull << (i * 4 + 3);
  }
  mb[idx] = bits;
}

// ---------------- Global attention (heads 0..7), bf16 MFMA flash -----------
// grid (L/64, 8, B), block 256 (4 waves). Wave w owns q-rows q0+16w..+15.
// 1-deep prefetch pipeline: tile kt+1's K/V (regs) + mask (u64) global loads
// issue right after the compute barrier; LDS writes happen at loop top after
// the end-of-tile barrier (issue-early / write-late). Single K/V LDS buffer.
__global__ __launch_bounds__(256) void attn_kernel(
    const float* __restrict__ q, const float* __restrict__ k,
    const float* __restrict__ v, const int* __restrict__ mask,
    const unsigned long long* __restrict__ mb, const int use_bits,
    float* __restrict__ out)
{
  extern __shared__ char smc[];
  char* sK  = smc;            // [64][64] bf16, swizzled rows (128B)
  char* sVT = smc + 8192;     // [64][64] bf16: VT[d][kcol], swizzled rows
  char* sP  = smc + 16384;    // wave w: [16][64] bf16 at +2048*w

  const int tid = threadIdx.x;
  const int q0 = blockIdx.x * 64;
  const int h  = blockIdx.y;
  const int b  = blockIdx.z;

  const int w  = tid >> 6;
  const int ln = tid & 63;
  const int lg = ln >> 4;        // lane group 0..3
  const int c  = ln & 15;        // lane col 0..15

  const size_t hbase = ((size_t)b * H_ + h) * L_ * DK_;
  const float* kp = k + hbase;
  const float* vp = v + hbase;
  const int*   mp = mask + (size_t)b * L_ * L_;
  const unsigned long long* mbp = mb + (size_t)b * L_ * 16;

  // Q A-fragments in registers: rows q0 + w*16 + c, d = kt*32 + lg*8 + i
  short8 qa[2];
  {
    const float* qrow = q + hbase + (size_t)(q0 + w * 16 + c) * DK_ + lg * 8;
#pragma unroll
    for (int kt = 0; kt < 2; ++kt) {
      const float4 f0 = *(const float4*)(qrow + kt * 32);
      const float4 f1 = *(const float4*)(qrow + kt * 32 + 4);
      qa[kt] = pack8(f0, f1);
    }
  }

  char* sPw = sP + w * 2048;

  f32x4 o_[4];
#pragma unroll
  for (int nt = 0; nt < 4; ++nt) { o_[nt][0] = 0.f; o_[nt][1] = 0.f; o_[nt][2] = 0.f; o_[nt][3] = 0.f; }
  float mrun[4], lrun[4];
#pragma unroll
  for (int r = 0; r < 4; ++r) { mrun[r] = -1e30f; lrun[r] = 0.f; }

  // staging role: row rr, 16-col chunk c16
  const int rr  = tid >> 2;
  const int c16 = (tid & 3) << 4;

  // ---- prologue: prefetch tile 0 into registers ----
  float4 kreg[4], vreg[4];
  unsigned long long mreg[4];
  {
    const float* ksrc = kp + (size_t)rr * DK_ + c16;
    kreg[0] = *(const float4*)(ksrc);      kreg[1] = *(const float4*)(ksrc + 4);
    kreg[2] = *(const float4*)(ksrc + 8);  kreg[3] = *(const float4*)(ksrc + 12);
    const float* vsrc = vp + (size_t)rr * DK_ + c16;
    vreg[0] = *(const float4*)(vsrc);      vreg[1] = *(const float4*)(vsrc + 4);
    vreg[2] = *(const float4*)(vsrc + 8);  vreg[3] = *(const float4*)(vsrc + 12);
    if (use_bits) {
#pragma unroll
      for (int r = 0; r < 4; ++r)
        mreg[r] = mbp[(size_t)(q0 + w * 16 + lg * 4 + r) * 16 + 0];
    }
  }

  for (int kt0 = 0; kt0 < 16; ++kt0) {
    // ---- write staged tile (registers) to LDS, swizzled ----
    {
      const int kb = rr * 128 + c16 * 2;
      const int sw = (rr & 7) << 4;
      *(uint4*)(sK + ((kb) ^ sw))      = packrow16(kreg[0], kreg[1]);
      *(uint4*)(sK + ((kb + 16) ^ sw)) = packrow16(kreg[2], kreg[3]);
      const float vv[16] = {vreg[0].x, vreg[0].y, vreg[0].z, vreg[0].w,
                            vreg[1].x, vreg[1].y, vreg[1].z, vreg[1].w,
                            vreg[2].x, vreg[2].y, vreg[2].z, vreg[2].w,
                            vreg[3].x, vreg[3].y, vreg[3].z, vreg[3].w};
#pragma unroll
      for (int j = 0; j < 16; ++j) {
        const int d = c16 + j;
        *(unsigned short*)(sVT + ((d * 128 + rr * 2) ^ ((d & 7) << 4))) = f2bf(vv[j]);
      }
    }
    __syncthreads();

    // capture this tile's mask words, then issue next tile's loads
    unsigned long long mcur[4];
#pragma unroll
    for (int r = 0; r < 4; ++r) mcur[r] = mreg[r];
    {
      const int ktn = (kt0 + 1) & 15;
      const float* ksrc = kp + (size_t)(ktn * 64 + rr) * DK_ + c16;
      kreg[0] = *(const float4*)(ksrc);      kreg[1] = *(const float4*)(ksrc + 4);
      kreg[2] = *(const float4*)(ksrc + 8);  kreg[3] = *(const float4*)(ksrc + 12);
      const float* vsrc = vp + (size_t)(ktn * 64 + rr) * DK_ + c16;
      vreg[0] = *(const float4*)(vsrc);      vreg[1] = *(const float4*)(vsrc + 4);
      vreg[2] = *(const float4*)(vsrc + 8);  vreg[3] = *(const float4*)(vsrc + 12);
      if (use_bits) {
#pragma unroll
        for (int r = 0; r < 4; ++r)
          mreg[r] = mbp[(size_t)(q0 + w * 16 + lg * 4 + r) * 16 + ktn];
      }
    }

    // ---- S = Q K^T : 4 N-tiles x 2 K-chunks ----
    f32x4 acc[4];
#pragma unroll
    for (int nt = 0; nt < 4; ++nt) {
      acc[nt][0] = 0.f; acc[nt][1] = 0.f; acc[nt][2] = 0.f; acc[nt][3] = 0.f;
#pragma unroll
      for (int kt = 0; kt < 2; ++kt) {
        const int off = (((nt * 16 + c) * 128 + kt * 64 + lg * 16) ^ ((c & 7) << 4));
        const short8 bk = __builtin_bit_cast(short8, *(const uint4*)(sK + off));
        acc[nt] = MFMA_BF16(qa[kt], bk, acc[nt]);
      }
    }

    // ---- mask + online softmax (rows lg*4+r; 16 c-lanes share a row) ----
#pragma unroll
    for (int r = 0; r < 4; ++r) {
      bool k0_, k1_, k2_, k3_;
      if (use_bits) {
        const unsigned long long mword = mcur[r];
        k0_ = (mword >> (c)) & 1ull;
        k1_ = (mword >> (16 + c)) & 1ull;
        k2_ = (mword >> (32 + c)) & 1ull;
        k3_ = (mword >> (48 + c)) & 1ull;
      } else {
        const int qr = q0 + w * 16 + lg * 4 + r;
        const int* mrow = mp + (size_t)qr * L_ + kt0 * 64 + c;
        k0_ = mrow[0] != 0; k1_ = mrow[16] != 0; k2_ = mrow[32] != 0; k3_ = mrow[48] != 0;
      }
      const float s0_ = k0_ ? acc[0][r] * 0.125f : -1e12f;
      const float s1_ = k1_ ? acc[1][r] * 0.125f : -1e12f;
      const float s2_ = k2_ ? acc[2][r] * 0.125f : -1e12f;
      const float s3_ = k3_ ? acc[3][r] * 0.125f : -1e12f;
      float mt = fmaxf(fmaxf(s0_, s1_), fmaxf(s2_, s3_));
#pragma unroll
      for (int off = 1; off < 16; off <<= 1) mt = fmaxf(mt, __shfl_xor(mt, off));
      const float mnew = fmaxf(mrun[r], mt);
      const float p0 = __expf(s0_ - mnew);
      const float p1 = __expf(s1_ - mnew);
      const float p2 = __expf(s2_ - mnew);
      const float p3 = __expf(s3_ - mnew);
      float pt = p0 + p1 + p2 + p3;
#pragma unroll
      for (int off = 1; off < 16; off <<= 1) pt += __shfl_xor(pt, off);
      const float scale = __expf(mrun[r] - mnew);
      mrun[r] = mnew;
      lrun[r] = lrun[r] * scale + pt;
      o_[0][r] *= scale; o_[1][r] *= scale; o_[2][r] *= scale; o_[3][r] *= scale;
      const int prow = lg * 4 + r;
      const int pb = prow * 128;
      const int psw = (prow & 7) << 4;
      *(unsigned short*)(sPw + ((pb + (c * 2)) ^ psw))       = f2bf(p0);
      *(unsigned short*)(sPw + ((pb + (16 + c) * 2) ^ psw))  = f2bf(p1);
      *(unsigned short*)(sPw + ((pb + (32 + c) * 2) ^ psw))  = f2bf(p2);
      *(unsigned short*)(sPw + ((pb + (48 + c) * 2) ^ psw))  = f2bf(p3);
    }

    // ---- O += P V  (A = P from wave-private LDS, B = V^T) ----
#pragma unroll
    for (int kt = 0; kt < 2; ++kt) {
      const int aoff = ((c * 128 + kt * 64 + lg * 16) ^ ((c & 7) << 4));
      const short8 pa = __builtin_bit_cast(short8, *(const uint4*)(sPw + aoff));
#pragma unroll
      for (int nt = 0; nt < 4; ++nt) {
        const int boff = (((nt * 16 + c) * 128 + kt * 64 + lg * 16) ^ ((c & 7) << 4));
        const short8 bv = __builtin_bit_cast(short8, *(const uint4*)(sVT + boff));
        o_[nt] = MFMA_BF16(pa, bv, o_[nt]);
      }
    }
    __syncthreads();
  }

  // ---- finalize: divide by l, store f32 ----
  float* op = out + (((size_t)b * 24 + h) * L_ + q0 + w * 16) * DK_;
#pragma unroll
  for (int r = 0; r < 4; ++r) {
    const float inv = 1.f / lrun[r];
#pragma unroll
    for (int nt = 0; nt < 4; ++nt)
      op[(size_t)(lg * 4 + r) * DK_ + nt * 16 + c] = o_[nt][r] * inv;
  }
}

// ---------------- GRU (heads 8..23), bf16 MFMA ------------------------------
// grid (L/128, 16, B), block 512 (8 waves). Wave w owns 16 sequences; h state
// f32 in C-fragments; h round-trips wave-private LDS as bf16 hi/lo.
// XG is stored TRANSPOSED [192 j][148 pos] (stride 296B) and prefetched fully
// into registers (36 ds_read_b64) before the 9-step loop -> zero in-loop XG
// LDS traffic (round-4 counters showed the 48 dependent scalar u16 reads/step
// were the dominant latency exposure). ts-loop fully unrolled so all window
// indices are compile-time (rule #20).
__global__ __launch_bounds__(512) void gru_kernel(
    const float* __restrict__ value, const float* __restrict__ wih_g,
    const float* __restrict__ whh_g, const float* __restrict__ bih_g,
    const float* __restrict__ bhh_g, float* __restrict__ out)
{
  extern __shared__ char smc[];
  char*  sW   = smc + GRU_W_OFF;       // W_hh bf16 swz [192][64]
  char*  sXGT = smc + GRU_XGT_OFF;     // bf16 [192 j][148 pos], stride 296B
  char*  sHB  = smc + GRU_HB_OFF;      // per-wave h hi/lo
  float* sBih = (float*)(smc + GRU_BIH_OFF);  // [192]

  const int tid  = threadIdx.x;
  const int l0   = blockIdx.x * 128;
  const int gset = blockIdx.y >> 2;
  const int vh   = blockIdx.y & 3;
  const int b    = blockIdx.z;

  const float* vp   = value + (((size_t)b * H_ + GH_ + vh) * L_) * DK_;
  const float* wih  = wih_g + (size_t)gset * 192 * DK_;
  const float* whh  = whh_g + (size_t)gset * 192 * DK_;
  const float* bihp = bih_g + gset * 192;
  const float* bhhp = bhh_g + gset * 192;

  if (tid < 192) sBih[tid] = bihp[tid];
#pragma unroll
  for (int k2 = 0; k2 < 4; ++k2) {
    uint4 z; z.x = 0u; z.y = 0u; z.z = 0u; z.w = 0u;
    *(uint4*)(sHB + ((size_t)tid + 512 * k2) * 16) = z;
  }
  for (int cid = tid; cid < 1536; cid += 512) {   // 192 rows * 8 chunks(16B)
    const int row = cid >> 3, ch = cid & 7;
    const float* wp = whh + row * 64 + ch * 8;
    const float4 w0 = *(const float4*)wp;
    const float4 w1 = *(const float4*)(wp + 4);
    *(uint4*)(sW + ((row * 128 + ch * 16) ^ ((row & 7) << 4))) = packrow16(w0, w1);
  }
  __syncthreads();

  const int w  = tid >> 6;
  const int ln = tid & 63;
  const int lg = ln >> 4;
  const int c  = ln & 15;

  // ---- phase 1: XGT[j][pos] = v[pos]·W_ih[j] + b_ih[j] (b64 packed write) --
  for (int t = w; t < 108; t += 8) {
    const int Mt = t / 12, Nt = t - Mt * 12;
    const int row = l0 + Mt * 16 + c;
    const bool valid = row < L_;
    const float* va = vp + (size_t)row * 64 + lg * 8;
    float4 z4; z4.x = 0.f; z4.y = 0.f; z4.z = 0.f; z4.w = 0.f;
    const float4 a00 = valid ? *(const float4*)(va)      : z4;
    const float4 a01 = valid ? *(const float4*)(va + 4)  : z4;
    const float4 a10 = valid ? *(const float4*)(va + 32) : z4;
    const float4 a11 = valid ? *(const float4*)(va + 36) : z4;
    const float* wb = wih + (size_t)(Nt * 16 + c) * 64 + lg * 8;
    const float4 b00 = *(const float4*)(wb);
    const float4 b01 = *(const float4*)(wb + 4);
    const float4 b10 = *(const float4*)(wb + 32);
    const float4 b11 = *(const float4*)(wb + 36);
    f32x4 acc = {0.f, 0.f, 0.f, 0.f};
    acc = MFMA_BF16(pack8(a00, a01), pack8(b00, b01), acc);
    acc = MFMA_BF16(pack8(a10, a11), pack8(b10, b11), acc);
    const float bias = sBih[Nt * 16 + c];
    const int pos0 = Mt * 16 + lg * 4;
    const int jj = Nt * 16 + c;
    uint2 pk;
    pk.x = (unsigned)f2bf(acc[0] + bias) | ((unsigned)f2bf(acc[1] + bias) << 16);
    pk.y = (unsigned)f2bf(acc[2] + bias) | ((unsigned)f2bf(acc[3] + bias) << 16);
    *(uint2*)(sXGT + jj * XGT_STRIDE + pos0 * 2) = pk;
  }
  __syncthreads();

  char* hbH = sHB + w * 4096;
  char* hbL = hbH + 2048;
  const int seqB = w * 16;

  float bhh[12];
#pragma unroll
  for (int n = 0; n < 12; ++n) bhh[n] = bhhp[n * 16 + c];

  // ---- prefetch this lane's XG window: pos P0..P0+11, rows j=g*64+t*16+c ----
  const int P0 = seqB + lg * 4;
  uint2 xgq[4][3][3];
#pragma unroll
  for (int t = 0; t < 4; ++t)
#pragma unroll
    for (int g = 0; g < 3; ++g) {
      const char* rowp = sXGT + (g * 64 + t * 16 + c) * XGT_STRIDE + P0 * 2;
#pragma unroll
      for (int kk = 0; kk < 3; ++kk)
        xgq[t][g][kk] = *(const uint2*)(rowp + kk * 8);
    }

  f32x4 hfr[4];
#pragma unroll
  for (int t = 0; t < 4; ++t) { hfr[t][0] = 0.f; hfr[t][1] = 0.f; hfr[t][2] = 0.f; hfr[t][3] = 0.f; }

#pragma unroll
  for (int ts = 0; ts < WS_; ++ts) {
    short8 ahi[2], alo[2];
#pragma unroll
    for (int kt = 0; kt < 2; ++kt) {
      const int ao = (c * 128 + kt * 64 + lg * 16) ^ ((c & 7) << 4);
      ahi[kt] = __builtin_bit_cast(short8, *(const uint4*)(hbH + ao));
      alo[kt] = __builtin_bit_cast(short8, *(const uint4*)(hbL + ao));
    }
    f32x4 acc[12];
#pragma unroll
    for (int n = 0; n < 12; ++n) {
      acc[n][0] = 0.f; acc[n][1] = 0.f; acc[n][2] = 0.f; acc[n][3] = 0.f;
#pragma unroll
      for (int kt = 0; kt < 2; ++kt) {
        const int wo = ((n * 16 + c) * 128 + kt * 64 + lg * 16) ^ ((c & 7) << 4);
        const short8 bw = __builtin_bit_cast(short8, *(const uint4*)(sW + wo));
        acc[n] = MFMA_BF16(ahi[kt], bw, acc[n]);
        acc[n] = MFMA_BF16(alo[kt], bw, acc[n]);
      }
    }
#pragma unroll
    for (int t = 0; t < 4; ++t) {
#pragma unroll
      for (int r = 0; r < 4; ++r) {
        const int wi = r + ts;                 // compile-time after unroll
        const float xr = xg_get(xgq[t][0], wi);
        const float xz = xg_get(xgq[t][1], wi);
        const float xn = xg_get(xgq[t][2], wi);
        const float ghr = acc[t][r] + bhh[t];
        const float ghz = acc[t + 4][r] + bhh[t + 4];
        const float ghn = acc[t + 8][r] + bhh[t + 8];
        const float rr = __builtin_amdgcn_rcpf(1.f + __expf(-(xr + ghr)));
        const float zz = __builtin_amdgcn_rcpf(1.f + __expf(-(xz + ghz)));
        const float e2 = __expf(2.f * (xn + rr * ghn));
        const float nn = 1.f - 2.f * __builtin_amdgcn_rcpf(1.f + e2);
        float h = hfr[t][r];
        h = (1.f - zz) * nn + zz * h;
        hfr[t][r] = h;
        const int sl = lg * 4 + r;
        const int d = c + 16 * t;
        const int hb = (sl * 128 + d * 2) ^ ((sl & 7) << 4);
        const unsigned short hhi = f2bf(h);
        *(unsigned short*)(hbH + hb) = hhi;
        *(unsigned short*)(hbL + hb) = f2bf(h - bf2f(hhi));
      }
    }
  }

  float* op = out + (((size_t)b * 24 + (GH_ + gset * 4 + vh)) * L_ + l0) * DK_;
#pragma unroll
  for (int t = 0; t < 4; ++t)
#pragma unroll
    for (int r = 0; r < 4; ++r)
      op[(size_t)(seqB + lg * 4 + r) * 64 + c + 16 * t] = hfr[t][r];
}

extern "C" void kernel_launch(void* const* d_in, const int* in_sizes, int n_in,
                              void* d_out, int out_size, void* d_ws, size_t ws_size,
                              hipStream_t stream) {
  (void)in_sizes; (void)n_in; (void)out_size;
  const float* q   = (const float*)d_in[0];
  const float* k   = (const float*)d_in[1];
  const float* v   = (const float*)d_in[2];
  const int*   msk = (const int*)d_in[3];
  const float* wih = (const float*)d_in[4];
  const float* whh = (const float*)d_in[5];
  const float* bih = (const float*)d_in[6];
  const float* bhh = (const float*)d_in[7];
  float* out = (float*)d_out;

  const int use_bits = (ws_size >= (size_t)MB_WORDS * 8) ? 1 : 0;
  unsigned long long* mb = (unsigned long long*)d_ws;

  (void)hipFuncSetAttribute((const void*)gru_kernel,
                            hipFuncAttributeMaxDynamicSharedMemorySize, GRU_LDS_BYTES);

  if (use_bits)
    maskpack_kernel<<<dim3(MB_WORDS / 256), dim3(256), 0, stream>>>(msk, mb);
  attn_kernel<<<dim3(L_ / 64, GH_, B_), dim3(256), ATTN_LDS_BYTES, stream>>>(
      q, k, v, msk, mb, use_bits, out);
  gru_kernel<<<dim3(L_ / 128, 16, B_), dim3(512), GRU_LDS_BYTES, stream>>>(
      v, wih, whh, bih, bhh, out);
}